// Round 6
// baseline (115.878 us; speedup 1.0000x reference)
//
#include <hip/hip_runtime.h>
#include <stdint.h>

// MinimumErrorRateLoss: unit-cost Levenshtein via Myers/Hyyrö bit-parallel DP.
// R6: 16-way u16 word split -> 131072 lanes = 2048 waves = 2 waves/SIMD.
// Lane owns a 16-bit word (w = lane&15): one DPP row = one 16-word chain, so
// the carry hand-off is still a single v_mov_dpp row_shr:1 and never crosses
// samples. u16 carry = bit16 of a plain 32-bit add (no addc); only nVP needs
// a 0xFFFF mask (all other high-bit garbage provably harmless).
//
// R5 analysis: 388 cyc/phase = 135 issue + ~250 exposed dep-chain latency at
// 1 wave/SIMD (chip full, zero TLP). 2 waves/SIMD (m114 co-scheduling) fills
// the chain bubbles; per-phase issue also drops (~45 VALU vs ~65).
//
// Layout (fixed problem size):
//   log_probs: (128, 64) f32      -> lp[b*64+s]
//   ref:       (256, 128) i32     -> ref[j*128+b]   (shared across samples)
//   hyp:       (256, 128, 64) i32 -> hyp[t*8192 + b*64 + s]
//   out:       scalar f32
// EOS = 0, INCLUDE_EOS -> len = first-EOS-idx + 1, else T.

#define BATCH   128
#define SAMPLES 64
#define RLEN    256
#define HLEN    256
#define NSEQ    (BATCH*SAMPLES)
#define NTOK    1000
#define NW16    16         // 256 ref positions / 16 bits
#define SPB     16         // samples per block
#define PMSTR   9          // pm row stride in u32 (8 data + 1 pad)
#define HTSTR   18         // ht row stride in u16 (16 data + 2 pad)

typedef unsigned long long u64;
typedef unsigned int       u32;

// DPP row_shr:1 -> lane i reads lane i-1 within rows of 16; row-lane-0 gets 0.
__device__ __forceinline__ int row_shr1(int x) {
    return __builtin_amdgcn_mov_dpp(x, 0x111, 0xf, 0xf, true);
}

__global__ __launch_bounds__(256) void mer_edit(const int* __restrict__ ref,
                                                const int* __restrict__ hyp,
                                                int* __restrict__ scores,
                                                int* __restrict__ reflen)
{
    const int blk  = blockIdx.x;      // 0..511
    const int b    = blk >> 2;        // batch element
    const int q    = blk & 3;         // sample quarter (16 samples)
    const int tid  = threadIdx.x;     // 0..255
    const int lane = tid & 63;
    const int w    = lane & 15;                        // u16 word 0..15
    const int sl   = (tid >> 6) * 4 + (lane >> 4);     // local sample 0..15

    __shared__ __align__(16) u32 pm[NTOK * PMSTR];            // 36000 B
    __shared__ __align__(16) unsigned short ht[HLEN * HTSTR]; //  9216 B
    __shared__ int m_sh;

    if (tid == 0) m_sh = RLEN;

    // ---- zero PM (9000 u32 = 2250 int4) ----
    for (int i = tid; i < (NTOK * PMSTR) / 4; i += 256)
        ((int4*)pm)[i] = int4{0, 0, 0, 0};

    // ---- stage this block's 16-sample hyp slab: 1024 int4, 4/thread ----
#pragma unroll
    for (int it = 0; it < 4; it++) {
        int idx = it * 256 + tid;     // int4 index
        int t   = idx >> 2;
        int s4  = (idx & 3) * 4;
        int4 v  = *(const int4*)(hyp + t * NSEQ + b * SAMPLES + q * SPB + s4);
        ushort4 u;
        u.x = (unsigned short)v.x; u.y = (unsigned short)v.y;
        u.z = (unsigned short)v.z; u.w = (unsigned short)v.w;
        *(ushort4*)&ht[t * HTSTR + s4] = u;
    }

    // ---- ref column: one token per thread (j = tid) ----
    const int rt = ref[tid * BATCH + b];
    __syncthreads();                  // m_sh + pm zero done
    if (rt == 0) atomicMin(&m_sh, tid);
    __syncthreads();
    const int m = (m_sh < RLEN) ? (m_sh + 1) : RLEN;   // ref_len, 1..256
    if (tid < m)
        atomicOr(&pm[rt * PMSTR + (tid >> 5)], 1u << (tid & 31));
    __syncthreads();                  // pm + ht ready; no more barriers

    // ---- systolic-in-wave Myers, u16 words (2 packed per pm u32) ----
    const int  sw   = (m - 1) >> 4, sb = (m - 1) & 15;  // score bit location
    const bool isW0 = (w == 0);
    const bool isSW = (w == sw);
    const int  hw   = w >> 1, hsh = (w & 1) * 16;       // pm u32 idx, half

    u32  VP = 0xFFFFu, VN = 0u;
    int  score = m;
    bool done  = false;

    // pipeline prime: tokens 3 ahead, Eq 2 ahead (t starts at -w; clamp)
    int tokA, tokB, tokC;
    u32 EqA, EqB;
    {
        int p0 = (0 - w) < 0 ? 0 : (0 - w);
        int p1 = (1 - w) < 0 ? 0 : (1 - w);
        int p2 = (2 - w) < 0 ? 0 : (2 - w);
        tokA = ht[p0 * HTSTR + sl];
        tokB = ht[p1 * HTSTR + sl];
        tokC = ht[p2 * HTSTR + sl];
        EqA  = (pm[tokA * PMSTR + hw] >> hsh) & 0xFFFFu;
        EqB  = (pm[tokB * PMSTR + hw] >> hsh) & 0xFFFFu;
    }

    int out_pkd = 0;   // packed (cout, hp15, hn15) from my previous phase
    int t = -w;        // this lane's current DP step

    for (int P = 0; P < HLEN + NW16 - 1; ++P, ++t) {
        int t3 = t + 3;
        t3 = (t3 < 0) ? 0 : ((t3 > HLEN - 1) ? (HLEN - 1) : t3);

        // prefetch (consumed 2-3 phases later; LDS latency covered)
        int tokD = ht[t3 * HTSTR + sl];
        u32 EqC  = (pm[tokC * PMSTR + hw] >> hsh) & 0xFFFFu;

        // carries from word w-1 (its previous-phase output), one DPP
        int inp = row_shr1(out_pkd);
        if (isW0) inp = 2;            // cin=0, hpin=1 (D[0][j]=j), hnin=0
        const u32 cin  = (u32)(inp & 1);
        const u32 hpin = (u32)((inp >> 1) & 1);
        const u32 hnin = (u32)((inp >> 2) & 1);

        // u16 Myers step in u32 regs. Clean (high bits zero): eq, VP, HN, VN'..
        // garbage-high tolerated: D0, HP, HPs, VN. Only nVP is re-masked.
        const u32 eq = EqA;
        const u32 x  = eq & VP;
        const u32 S  = x + VP + cin;              // bit16 = exact carry
        const u32 D0 = (S ^ VP) | eq | VN;
        const u32 HP = VN | ~(D0 | VP);
        const u32 HN = VP & D0;                   // clean
        const u32 HPs = (HP << 1) | hpin;
        const u32 HNs = (HN << 1) | hnin;
        const u32 nVP = (HNs | ~(D0 | HPs)) & 0xFFFFu;
        const u32 nVN = HPs & D0;

        out_pkd = (int)(((S >> 16) & 1u) | (((HP >> 15) & 1u) << 1)
                        | (((HN >> 15) & 1u) << 2));

        const bool valid = ((u32)t < (u32)HLEN) && !done;
        if (valid) {
            VP = nVP; VN = nVN;
            if (isSW)
                score += (int)((HP >> sb) & 1u) - (int)((HN >> sb) & 1u);
            if (tokA == 0) done = true;   // processed first hyp EOS -> freeze
        }

        tokA = tokB; tokB = tokC; tokC = tokD;
        EqA  = EqB;  EqB  = EqC;
    }

    if (isSW) scores[b * SAMPLES + q * SPB + sl] = score;
    if (q == 0 && tid == 0) reflen[b] = m;
}

// Grid 128 x 64 threads: per-batch f64 loss partial.
//   sum_s (er - mean_er)*softmax = dot(er,p)/sumexp - mean_er  (sum p = 1)
__global__ __launch_bounds__(64) void mer_loss(const float* __restrict__ lp,
                                               const int* __restrict__ scores,
                                               const int* __restrict__ reflen,
                                               double* __restrict__ partial)
{
    const int b = blockIdx.x, s = threadIdx.x;
    double er = (double)scores[b * SAMPLES + s] / (double)reflen[b];
    double x  = (double)lp[b * SAMPLES + s];
    double mx = x;
#pragma unroll
    for (int off = 32; off > 0; off >>= 1)
        mx = fmax(mx, __shfl_xor(mx, off));
    double e = exp(x - mx);
    double se = e, see = er * e, ser = er;
#pragma unroll
    for (int off = 32; off > 0; off >>= 1) {
        se  += __shfl_xor(se,  off);
        see += __shfl_xor(see, off);
        ser += __shfl_xor(ser, off);
    }
    if (s == 0) partial[b] = see / se - ser * (1.0 / SAMPLES);
}

// 1 block, 64 threads: sum 128 per-batch partials, scale, write scalar.
__global__ __launch_bounds__(64) void mer_final(const double* __restrict__ partial,
                                                float* __restrict__ out)
{
    const int tid = threadIdx.x;
    double v = partial[tid] + partial[tid + 64];
#pragma unroll
    for (int off = 32; off > 0; off >>= 1)
        v += __shfl_xor(v, off);
    if (tid == 0) out[0] = (float)(v / (double)(BATCH * SAMPLES));
}

extern "C" void kernel_launch(void* const* d_in, const int* in_sizes, int n_in,
                              void* d_out, int out_size, void* d_ws, size_t ws_size,
                              hipStream_t stream)
{
    const float* lp  = (const float*)d_in[0];
    const int*   ref = (const int*)d_in[1];
    const int*   hyp = (const int*)d_in[2];

    double* partial = (double*)d_ws;                   // 128 f64
    int*    scores  = (int*)(partial + BATCH);         // 8192 i32
    int*    reflen  = scores + NSEQ;                   // 128 i32
    float*  out     = (float*)d_out;

    mer_edit<<<4 * BATCH, 256, 0, stream>>>(ref, hyp, scores, reflen);
    mer_loss<<<BATCH, 64, 0, stream>>>(lp, scores, reflen, partial);
    mer_final<<<1, 64, 0, stream>>>(partial, out);
}

// Round 7
// 92.598 us; speedup vs baseline: 1.2514x; 1.2514x over previous
//
#include <hip/hip_runtime.h>
#include <stdint.h>

// MinimumErrorRateLoss: unit-cost Levenshtein via Myers/Hyyrö bit-parallel DP.
// R7: u32 8-way word split (R5 mapping) + R=4 DP STEPS PER SYSTOLIC PHASE.
// R6 post-mortem: per-phase cost is ~55-60 fixed-overhead instrs + ~15-20
// bit-math; narrowing words multiplied overhead. Fix: amortize — each phase
// handles 4 consecutive hyp steps; the carry packet (4 x {cout,hp,hn} = 12
// bits in one int) still crosses words with ONE v_mov_dpp row_shr:1.
// Phases: 263 -> 72. hyp tokens staged TRANSPOSED in LDS so a phase's 4
// tokens are one aligned ds_read_b64. VP/VN freeze replaced by score-freeze
// (state may evolve past hyp-EOS; accumulation stops — recurrence stays
// well-defined), saving 2 cndmasks/step.
//
// Layout (fixed problem size):
//   log_probs: (128, 64) f32      -> lp[b*64+s]
//   ref:       (256, 128) i32     -> ref[j*128+b]   (shared across samples)
//   hyp:       (256, 128, 64) i32 -> hyp[t*8192 + b*64 + s]
//   out:       scalar f32
// EOS = 0, INCLUDE_EOS -> len = first-EOS-idx + 1, else T.

#define BATCH   128
#define SAMPLES 64
#define RLEN    256
#define HLEN    256
#define NSEQ    (BATCH*SAMPLES)
#define NTOK    1000
#define NWW     8          // 256 ref positions / 32 bits
#define SPB     32         // samples per block
#define PMSTR   9          // pm row stride in u32 (8 data + 1 pad)
#define HTROW   260        // transposed ht row length in u16 (256 + 4 pad)
#define RSTEP   4          // DP steps per systolic phase
#define NPH     72         // ceil(256/4) + 8 - 1 = 71, +1 dead (even)

typedef unsigned long long u64;
typedef unsigned int       u32;

// DPP row_shr:1 -> lane i reads lane i-1 within rows of 16; row-lane-0 gets 0.
__device__ __forceinline__ int row_shr1(int x) {
    return __builtin_amdgcn_mov_dpp(x, 0x111, 0xf, 0xf, true);
}

__global__ __launch_bounds__(256) void mer_edit(const int* __restrict__ ref,
                                                const int* __restrict__ hyp,
                                                int* __restrict__ scores,
                                                int* __restrict__ reflen)
{
    const int blk  = blockIdx.x;      // 0..255
    const int b    = blk >> 1;        // batch element
    const int half = blk & 1;         // sample half (0: s 0..31, 1: s 32..63)
    const int tid  = threadIdx.x;     // 0..255
    const int w    = tid & 7;         // u32 word 0..7
    const int sl   = tid >> 3;        // local sample 0..31

    __shared__ __align__(16) u32 pm[NTOK * PMSTR];            // 36000 B
    __shared__ __align__(8)  unsigned short ht[SPB * HTROW];  // 16640 B (transposed)
    __shared__ int m_sh;

    if (tid == 0) m_sh = RLEN;

    // ---- zero PM (9000 u32 = 2250 int4) ----
    for (int i = tid; i < (NTOK * PMSTR) / 4; i += 256)
        ((int4*)pm)[i] = int4{0, 0, 0, 0};

    // ---- stage hyp slab TRANSPOSED: ht[s][t], 2048 int4 loads, u16 scatter ----
#pragma unroll
    for (int it = 0; it < 8; it++) {
        int idx = it * 256 + tid;     // int4 index
        int t   = idx >> 3;           // 0..255
        int s4  = (idx & 7) * 4;      // 0,4,..,28
        int4 v  = *(const int4*)(hyp + t * NSEQ + b * SAMPLES + half * SPB + s4);
        ht[(s4 + 0) * HTROW + t] = (unsigned short)v.x;
        ht[(s4 + 1) * HTROW + t] = (unsigned short)v.y;
        ht[(s4 + 2) * HTROW + t] = (unsigned short)v.z;
        ht[(s4 + 3) * HTROW + t] = (unsigned short)v.w;
    }

    // ---- ref column: one token per thread (j = tid) ----
    const int rt = ref[tid * BATCH + b];
    __syncthreads();                  // m_sh + pm zero done
    if (rt == 0) atomicMin(&m_sh, tid);
    __syncthreads();
    const int m = (m_sh < RLEN) ? (m_sh + 1) : RLEN;   // ref_len, 1..256
    if (tid < m)
        atomicOr(&pm[rt * PMSTR + (tid >> 5)], 1u << (tid & 31));
    __syncthreads();                  // pm + ht ready; no more barriers

    // ---- systolic-in-wave Myers, u32 words, 4 steps/phase ----
    const int  sw   = (m - 1) >> 5, sb = (m - 1) & 31;  // score bit location
    const bool isW0 = (w == 0);
    const bool isSW = (w == sw);
    const u32* pmw   = pm + w;                 // Eq column for my word
    const unsigned short* htrow = ht + sl * HTROW;

    u32  VP = ~0u, VN = 0u;
    int  score = m;
    bool done  = false;

    int base = -(w << 2);             // step index of this phase's first step

    // prime: tokens for phase 0 and 1 (clamped; garbage unused pre-skew)
    int c0 = base     < 0 ? 0 : base;
    int c1 = base + 4 < 0 ? 0 : base + 4;
    uint2 tkA = *(const uint2*)(htrow + c0);   // 4 u16 tokens, phase P
    uint2 tkB = *(const uint2*)(htrow + c1);   // phase P+1
    u32 eqA0, eqA1, eqA2, eqA3;
    {
        u32 p0 = tkA.x & 0xFFFFu, p1 = tkA.x >> 16;
        u32 p2 = tkA.y & 0xFFFFu, p3 = tkA.y >> 16;
        eqA0 = pmw[p0 * PMSTR]; eqA1 = pmw[p1 * PMSTR];
        eqA2 = pmw[p2 * PMSTR]; eqA3 = pmw[p3 * PMSTR];
    }

    int out_pkd = 0;   // 12-bit carry packet from my previous phase

#define STEP(EQ, TK, I) do {                                              \
        u32 cin  = ((u32)inp >> (I)) & 1u;                                \
        u32 hpin = ((u32)inp >> (8 + (I))) & 1u;                          \
        u32 hnin = ((u32)inp >> (16 + (I))) & 1u;                         \
        u32 x  = (EQ) & VP;                                               \
        u64 S  = (u64)x + VP + cin;                                       \
        u32 s2 = (u32)S;                                                  \
        u32 D0 = (s2 ^ VP) | (EQ) | VN;                                   \
        u32 HP = VN | ~(D0 | VP);                                         \
        u32 HN = VP & D0;                                                 \
        nout |= ((u32)(S >> 32) << (I)) | ((HP >> 31) << (8 + (I)))       \
                | ((HN >> 31) << (16 + (I)));                             \
        int delta = (int)((HP >> sb) & 1u) - (int)((HN >> sb) & 1u);      \
        u32 HPs = (HP << 1) | hpin;                                       \
        u32 HNs = (HN << 1) | hnin;                                       \
        if (pvalid) {                                                     \
            VP = HNs | ~(D0 | HPs);                                       \
            VN = HPs & D0;                                                \
            if (!done) {                                                  \
                score += delta;                                           \
                if ((TK) == 0) done = true;   /* EOS processed: freeze */ \
            }                                                             \
        }                                                                 \
    } while (0)

#pragma unroll 2
    for (int P = 0; P < NPH; ++P) {
        // token load for phase P+2
        int tl = base + 8;
        tl = tl < 0 ? 0 : (tl > (HLEN - RSTEP) ? (HLEN - RSTEP) : tl);
        uint2 tkC = *(const uint2*)(htrow + tl);

        // Eq loads for phase P+1 (tokens tkB, loaded last phase)
        u32 n0 = tkB.x & 0xFFFFu, n1 = tkB.x >> 16;
        u32 n2 = tkB.y & 0xFFFFu, n3 = tkB.y >> 16;
        u32 eqB0 = pmw[n0 * PMSTR], eqB1 = pmw[n1 * PMSTR];
        u32 eqB2 = pmw[n2 * PMSTR], eqB3 = pmw[n3 * PMSTR];

        // carry packet from word w-1 (its previous phase), one DPP
        int inp = row_shr1(out_pkd);
        if (isW0) inp = 0x0F00;       // cin=0, hpin=1 (D[0][j]=j), hnin=0 x4

        const bool pvalid = ((u32)base < (u32)HLEN);  // whole phase in range
        u32 nout = 0;
        u32 a0 = tkA.x & 0xFFFFu, a1 = tkA.x >> 16;
        u32 a2 = tkA.y & 0xFFFFu, a3 = tkA.y >> 16;
        STEP(eqA0, a0, 0);
        STEP(eqA1, a1, 1);
        STEP(eqA2, a2, 2);
        STEP(eqA3, a3, 3);
        out_pkd = (int)nout;

        // rotate pipeline
        tkA = tkB; tkB = tkC;
        eqA0 = eqB0; eqA1 = eqB1; eqA2 = eqB2; eqA3 = eqB3;
        base += RSTEP;
    }
#undef STEP

    if (isSW) scores[b * SAMPLES + half * SPB + sl] = score;
    if (half == 0 && tid == 0) reflen[b] = m;
}

// Grid 128 x 64 threads: per-batch f64 loss partial.
//   sum_s (er - mean_er)*softmax = dot(er,p)/sumexp - mean_er  (sum p = 1)
__global__ __launch_bounds__(64) void mer_loss(const float* __restrict__ lp,
                                               const int* __restrict__ scores,
                                               const int* __restrict__ reflen,
                                               double* __restrict__ partial)
{
    const int b = blockIdx.x, s = threadIdx.x;
    double er = (double)scores[b * SAMPLES + s] / (double)reflen[b];
    double x  = (double)lp[b * SAMPLES + s];
    double mx = x;
#pragma unroll
    for (int off = 32; off > 0; off >>= 1)
        mx = fmax(mx, __shfl_xor(mx, off));
    double e = exp(x - mx);
    double se = e, see = er * e, ser = er;
#pragma unroll
    for (int off = 32; off > 0; off >>= 1) {
        se  += __shfl_xor(se,  off);
        see += __shfl_xor(see, off);
        ser += __shfl_xor(ser, off);
    }
    if (s == 0) partial[b] = see / se - ser * (1.0 / SAMPLES);
}

// 1 block, 64 threads: sum 128 per-batch partials, scale, write scalar.
__global__ __launch_bounds__(64) void mer_final(const double* __restrict__ partial,
                                                float* __restrict__ out)
{
    const int tid = threadIdx.x;
    double v = partial[tid] + partial[tid + 64];
#pragma unroll
    for (int off = 32; off > 0; off >>= 1)
        v += __shfl_xor(v, off);
    if (tid == 0) out[0] = (float)(v / (double)(BATCH * SAMPLES));
}

extern "C" void kernel_launch(void* const* d_in, const int* in_sizes, int n_in,
                              void* d_out, int out_size, void* d_ws, size_t ws_size,
                              hipStream_t stream)
{
    const float* lp  = (const float*)d_in[0];
    const int*   ref = (const int*)d_in[1];
    const int*   hyp = (const int*)d_in[2];

    double* partial = (double*)d_ws;                   // 128 f64
    int*    scores  = (int*)(partial + BATCH);         // 8192 i32
    int*    reflen  = scores + NSEQ;                   // 128 i32
    float*  out     = (float*)d_out;

    mer_edit<<<2 * BATCH, 256, 0, stream>>>(ref, hyp, scores, reflen);
    mer_loss<<<BATCH, 64, 0, stream>>>(lp, scores, reflen, partial);
    mer_final<<<1, 64, 0, stream>>>(partial, out);
}